// Round 6
// baseline (673.081 us; speedup 1.0000x reference)
//
#include <hip/hip_runtime.h>
#include <stdint.h>

#define B_ 8
#define S_ 2048
#define H_ 512
#define R_ 7
#define K_ 10
#define L_ 4
#define KT_ 4096  // fused K dim: 7 relation slices + self slice
#define RH_ 3584  // R*H

typedef __attribute__((ext_vector_type(8))) short bf16x8;
typedef __attribute__((ext_vector_type(4))) float f32x4;
typedef __attribute__((ext_vector_type(4))) unsigned short u16x4;
typedef unsigned long long u64;

__device__ __forceinline__ unsigned short f2bf(float f){
  unsigned int u = __float_as_uint(f);
  u = (u + 0x7fffu + ((u >> 16) & 1u)) >> 16;  // RNE
  return (unsigned short)u;
}

__device__ __forceinline__ float bf2f(unsigned short s){
  return __uint_as_float(((unsigned int)s) << 16);
}

__device__ __forceinline__ f32x4 bf4load(const unsigned short* p){
  u16x4 v = *(const u16x4*)p;
  f32x4 o;
#pragma unroll
  for (int e = 0; e < 4; e++) o[e] = bf2f(v[e]);
  return o;
}

__device__ __forceinline__ void gload16(const void* g, void* lds){
  __builtin_amdgcn_global_load_lds(
      (const __attribute__((address_space(1))) unsigned int*)g,
      (__attribute__((address_space(3))) unsigned int*)lds, 16, 0, 0);
}

// ---------------- KNN: per (b,i) find 10 nearest (excl self), exact f32 ops ---
__global__ __launch_bounds__(256) void knn_kernel(const float* __restrict__ pos,
                                                  int* __restrict__ knn){
  __shared__ float4 p4[S_];
  int b = blockIdx.y;
  const float* p = pos + (size_t)b * S_ * 3;
  for (int idx = threadIdx.x; idx < S_; idx += 256){
    float4 v; v.x = p[idx*3+0]; v.y = p[idx*3+1]; v.z = p[idx*3+2]; v.w = 0.f;
    p4[idx] = v;
  }
  __syncthreads();
  int w = threadIdx.x >> 6, l = threadIdx.x & 63;
  int i = blockIdx.x * 4 + w;
  float4 pi = p4[i];
  float xi = pi.x, yi = pi.y, zi = pi.z;
  u64 best[10];
#pragma unroll
  for (int q = 0; q < 10; q++) best[q] = ~0ull;
  for (int j = l; j < S_; j += 64){
    if (j == i) continue;
    float4 pj = p4[j];
    float dx = __fsub_rn(xi, pj.x);
    float dy = __fsub_rn(yi, pj.y);
    float dz = __fsub_rn(zi, pj.z);
    float d2 = __fadd_rn(__fadd_rn(__fmul_rn(dx,dx), __fmul_rn(dy,dy)), __fmul_rn(dz,dz));
    u64 key = ((u64)__float_as_uint(d2) << 32) | (unsigned)j;  // lex (d2, j)
    if (key < best[9]){
      best[9] = key;
#pragma unroll
      for (int q = 9; q > 0; --q){      // one bubble pass (rest sorted)
        u64 a = best[q-1], c = best[q];
        u64 lo = a < c ? a : c, hi = a < c ? c : a;
        best[q-1] = lo; best[q] = hi;
      }
    }
  }
  int* out = knn + ((size_t)b * S_ + i) * K_;
#pragma unroll
  for (int t = 0; t < 10; t++){
    u64 cand = best[0];
    u64 m = cand;
#pragma unroll
    for (int o = 32; o; o >>= 1){
      u64 other = __shfl_xor(m, o);
      if (other < m) m = other;
    }
    if (cand == m){
#pragma unroll
      for (int q = 0; q < 9; q++) best[q] = best[q+1];
      best[9] = ~0ull;
    }
    if (l == 0) out[t] = (int)(unsigned)(m & 0xffffffffu);
  }
}

// ---------------- CSR build (transpose KNN adjacency) -----------------------
__global__ void count_kernel(const int* __restrict__ knn, int* __restrict__ counts){
  int idx = blockIdx.x * 256 + threadIdx.x;     // B*S*K total
  int b = idx / (S_ * K_);
  int d = knn[idx];
  atomicAdd(&counts[b * S_ + d], 1);
}

__global__ __launch_bounds__(256) void scan_kernel(const int* __restrict__ counts,
                                                   int* __restrict__ row_start,
                                                   int* __restrict__ cursor){
  __shared__ int lds[256];
  int b = blockIdx.x, t = threadIdx.x;
  int base = b * S_;
  int v[8]; int s = 0;
#pragma unroll
  for (int e = 0; e < 8; e++){ v[e] = s; s += counts[base + t*8 + e]; }
  lds[t] = s;
  __syncthreads();
  int total = s;
  for (int o = 1; o < 256; o <<= 1){
    int add = 0;
    if (t >= o) add = lds[t - o];
    __syncthreads();
    lds[t] += add;
    __syncthreads();
  }
  int ex = lds[t] - total;
  int rb = b * (S_ + 1);
#pragma unroll
  for (int e = 0; e < 8; e++){
    int val = ex + v[e];
    row_start[rb + t*8 + e] = val;
    cursor[base + t*8 + e] = val;
  }
  if (t == 255) row_start[rb + S_] = lds[255];
}

__global__ void fill_kernel(const int* __restrict__ knn, int* __restrict__ cursor,
                            int* __restrict__ col){
  int idx = blockIdx.x * 256 + threadIdx.x;     // B*S*K
  int b = idx / (S_ * K_);
  int i = (idx / K_) % S_;
  int d = knn[idx];
  int p = atomicAdd(&cursor[b * S_ + d], 1);
  col[(size_t)b * S_ * K_ + p] = i;
}

__global__ void sort_kernel(const int* __restrict__ row_start, int* __restrict__ col){
  int idx = blockIdx.x * 256 + threadIdx.x;     // B*S
  int b = idx / S_, d = idx % S_;
  int rs = row_start[b*(S_+1)+d], re = row_start[b*(S_+1)+d+1];
  int* c = col + (size_t)b * S_ * K_;
  for (int a = rs + 1; a < re; ++a){
    int vv = c[a]; int q = a - 1;
    while (q >= rs && c[q] > vv){ c[q+1] = c[q]; --q; }
    c[q+1] = vv;
  }
}

// ---------------- weight prep: Wt[l][j=512][k=4096] = [Wlin[l][j] | Wself[l][j]]
__global__ void prepw_kernel(const float* __restrict__ Wlin, const float* __restrict__ Wself,
                             unsigned short* __restrict__ Wt){
  size_t e = ((size_t)blockIdx.x * 256 + threadIdx.x) * 8;   // L*512*4096 elements
  int k = (int)(e & 4095);
  int j = (int)((e >> 12) & 511);
  int l = (int)(e >> 21);
  const float* src = (k < RH_) ? Wlin + ((size_t)l * H_ + j) * RH_ + k
                               : Wself + ((size_t)l * H_ + j) * H_ + (k - RH_);
  union { unsigned short s[8]; uint4 u; } pk;
#pragma unroll
  for (int t = 0; t < 8; t++) pk.s[t] = f2bf(src[t]);
  *(uint4*)&Wt[e] = pk.u;
}

__global__ void prepa_kernel(const float* __restrict__ gam, const float* __restrict__ bet,
                             const float* __restrict__ mean, const float* __restrict__ var,
                             const float* __restrict__ blin, const float* __restrict__ bself,
                             float* __restrict__ scale, float* __restrict__ shift){
  int idx = blockIdx.x * 256 + threadIdx.x;     // L*H
  float sc = gam[idx] * rsqrtf(var[idx] + 1e-5f);
  scale[idx] = sc;
  shift[idx] = bet[idx] + (blin[idx] + bself[idx] - mean[idx]) * sc;
}

// ---------------- h0 = pos @ Wp.T + bp --------------------------------------
__global__ void inith_kernel(const float* __restrict__ pos, const float* __restrict__ Wp,
                             const float* __restrict__ bp, float* __restrict__ h,
                             unsigned short* __restrict__ hb){
  int idx = blockIdx.x * 256 + threadIdx.x;     // B*S*(H/4)
  int j = (idx & 127) * 4;
  int bs = idx >> 7;
  const float* p = pos + (size_t)bs * 3;
  float x = p[0], y = p[1], z = p[2];
  f32x4 o;
#pragma unroll
  for (int e = 0; e < 4; e++){
    const float* wr = Wp + (j + e) * 3;
    o[e] = x * wr[0] + y * wr[1] + z * wr[2] + bp[j + e];
  }
  *(f32x4*)&h[(size_t)bs * H_ + j] = o;
  unsigned int w0 = f2bf(o[0]) | ((unsigned)f2bf(o[1]) << 16);
  unsigned int w1 = f2bf(o[2]) | ((unsigned)f2bf(o[3]) << 16);
  uint2 u; u.x = w0; u.y = w1;
  *(uint2*)&hb[(size_t)bs * H_ + j] = u;
}

// ---------------- hknn[d] = sum_{i: d in knn(i)} hb[i]  (bf16 out) ----------
__global__ __launch_bounds__(128) void hknn_kernel(const unsigned short* __restrict__ hb,
                                                   const int* __restrict__ row_start,
                                                   const int* __restrict__ col,
                                                   unsigned short* __restrict__ hk){
  int bx = blockIdx.x;
  int d = (bx & 7) * 256 + (bx >> 3);     // XCD-contiguous d chunks
  int b = blockIdx.y;
  int j = threadIdx.x * 4;
  int rs = row_start[b * (S_ + 1) + d];
  int re = row_start[b * (S_ + 1) + d + 1];
  const int* cl = col + (size_t)b * S_ * K_;
  f32x4 acc = {0.f, 0.f, 0.f, 0.f};
  for (int e = rs; e < re; ++e){
    int i = cl[e];
    acc += bf4load(&hb[((size_t)b * S_ + i) * H_ + j]);
  }
  u16x4 v;
#pragma unroll
  for (int e = 0; e < 4; e++) v[e] = f2bf(acc[e]);
  *(u16x4*)&hk[((size_t)b * S_ + d) * H_ + j] = v;
}

// ---------------- fused GEMM: out = [shifted-h slices | hknn | h] @ Wt.T ----
// M=16384, N=512, K=4096. BM=64, BN=128, BK=32 -> grid 1024 (4 blocks/CU).
// 4 waves (2x2 of 32x64), 3-slot LDS ring (36 KB), prefetch depth 2,
// counted s_waitcnt vmcnt(6), raw s_barriers, setprio around MFMA cluster,
// slot-XOR swizzled LDS, per-lane shifted global source (zero-page redirect),
// XCD-bijective block swizzle.
// Epilogue: BN affine + relu + residual -> h (f32) and hbout (bf16).
__global__ __launch_bounds__(256) void gemmf_kernel(
    const unsigned short* __restrict__ hbin,
    const unsigned short* __restrict__ hkn,
    const unsigned short* __restrict__ Wt,     // [512][4096] this layer
    float* __restrict__ h,
    unsigned short* __restrict__ hbout,
    const float* __restrict__ scale,           // [512] this layer
    const float* __restrict__ shift,
    const unsigned short* __restrict__ zbuf){
  __shared__ unsigned short As[3][64 * 32];
  __shared__ unsigned short Bs[3][128 * 32];
  int tid = threadIdx.x;
  int nwg = gridDim.x;          // 1024
  int q = nwg >> 3;
  int wg = blockIdx.x;
  int swz = (wg & 7) * q + (wg >> 3);
  int my = swz >> 2;            // 256 M tiles (4 N tiles, x fastest)
  int nx = swz & 3;
  int l = tid & 63, w = tid >> 6;
  int wrow = (w >> 1) * 32, wcol = (w & 1) * 64;
  int aBase = my * 64;
  int bBase = nx * 128;
  f32x4 acc[2][4] = {};

  // A staging: 64x32 tile, 1 chunk/thread. B staging: 128x32, 2 chunks/thread.
  int rowA = tid >> 2;
  int kcA = (tid & 3) ^ ((rowA >> 1) & 3);     // slot-XOR swizzle
  int gr0 = aBase + rowA;
  int rb0 = tid >> 2, rb1 = rb0 + 64;
  int kcB0 = (tid & 3) ^ ((rb0 >> 1) & 3);
  int kcB1 = (tid & 3) ^ ((rb1 >> 1) & 3);
  const unsigned short* Bb0 = Wt + (size_t)(bBase + rb0) * KT_ + kcB0 * 8;
  const unsigned short* Bb1 = Wt + (size_t)(bBase + rb1) * KT_ + kcB1 * 8;
  int dstA = tid * 8, dstB0 = tid * 8, dstB1 = (tid + 256) * 8;

  // stage-cursor slice pointers (stage leads compute by 2 K-steps)
  const unsigned short *sa0, *sb0, *sb1;

#define SETSLICE(rs) do {                                                     \
    int _r = (rs);                                                            \
    const unsigned short *_a0;                                                \
    if (_r < 6){                                                              \
      int _sh = (_r < 3) ? (3 - _r) : (2 - _r);   /* src = d - off_r */       \
      int _s0 = gr0 + _sh;                                                    \
      _a0 = (((unsigned)_s0 >> 11) == ((unsigned)gr0 >> 11)) ? hbin + (size_t)_s0 * H_ : zbuf; \
    } else {                                                                  \
      const unsigned short* _bs = (_r == 6) ? hkn : hbin;                     \
      _a0 = _bs + (size_t)gr0 * H_;                                           \
    }                                                                         \
    sa0 = _a0 + kcA * 8;                                                      \
    sb0 = Bb0 + _r * 512; sb1 = Bb1 + _r * 512;                               \
  } while (0)

#define STAGE(sl, ksl) do { int _ko = (ksl) * 32;          \
    gload16(sa0 + _ko, &As[sl][dstA]);                     \
    gload16(sb0 + _ko, &Bs[sl][dstB0]);                    \
    gload16(sb1 + _ko, &Bs[sl][dstB1]);                    \
  } while (0)

  SETSLICE(0);
  STAGE(0, 0); STAGE(1, 1);

  int kcr = l >> 4, lr = l & 15;
  int s = 0;
  for (int r = 0; r < 8; ++r){
#pragma unroll
    for (int ks = 0; ks < 16; ++ks){
      int s2 = s + 2; if (s2 >= 3) s2 -= 3;
      // stage K-step t+2 (t = r*16+ks) into slot s2
      if (r < 7 || ks < 14){
        if (ks == 14) SETSLICE(r + 1);
        STAGE(s2, (ks + 2) & 15);
      }
      // counted vmcnt: this slot's 3 loads landed; up to 6 in flight
      if (r < 7 || ks < 14)       asm volatile("s_waitcnt vmcnt(6)" ::: "memory");
      else if (ks == 14)          asm volatile("s_waitcnt vmcnt(3)" ::: "memory");
      else                        asm volatile("s_waitcnt vmcnt(0)" ::: "memory");
      __builtin_amdgcn_s_barrier();
      asm volatile("" ::: "memory");

      const unsigned short* Abuf = As[s];
      const unsigned short* Bbuf = Bs[s];
      bf16x8 af[2], bf[4];
#pragma unroll
      for (int mi = 0; mi < 2; mi++){
        int row = wrow + mi * 16 + lr;
        int slot = kcr ^ ((row >> 1) & 3);
        af[mi] = *(const bf16x8*)&Abuf[row * 32 + slot * 8];
      }
#pragma unroll
      for (int ni = 0; ni < 4; ni++){
        int row = wcol + ni * 16 + lr;
        int slot = kcr ^ ((row >> 1) & 3);
        bf[ni] = *(const bf16x8*)&Bbuf[row * 32 + slot * 8];
      }
      __builtin_amdgcn_s_setprio(1);
#pragma unroll
      for (int mi = 0; mi < 2; mi++)
#pragma unroll
        for (int ni = 0; ni < 4; ni++)
          acc[mi][ni] = __builtin_amdgcn_mfma_f32_16x16x32_bf16(af[mi], bf[ni], acc[mi][ni], 0, 0, 0);
      __builtin_amdgcn_s_setprio(0);
      asm volatile("" ::: "memory");
      __builtin_amdgcn_s_barrier();       // all waves done reading slot s
      asm volatile("" ::: "memory");
      ++s; if (s == 3) s = 0;
    }
  }
#undef STAGE
#undef SETSLICE

  // epilogue: BN affine + relu + residual
  int r0 = (l >> 4) * 4, c0 = l & 15;
#pragma unroll
  for (int ni = 0; ni < 4; ni++){
    int gcol = bBase + wcol + ni * 16 + c0;
    float sc = scale[gcol], sf = shift[gcol];
#pragma unroll
    for (int mi = 0; mi < 2; mi++){
#pragma unroll
      for (int reg = 0; reg < 4; reg++){
        int grow = aBase + wrow + mi * 16 + r0 + reg;
        size_t o = (size_t)grow * H_ + gcol;
        float val = fmaxf(acc[mi][ni][reg] * sc + sf, 0.f);
        float hv = h[o] + val;
        h[o] = hv;
        hbout[o] = f2bf(hv);
      }
    }
  }
}

extern "C" void kernel_launch(void* const* d_in, const int* in_sizes, int n_in,
                              void* d_out, int out_size, void* d_ws, size_t ws_size,
                              hipStream_t stream){
  const float* ca    = (const float*)d_in[1];
  const float* Wp    = (const float*)d_in[3];
  const float* bp    = (const float*)d_in[4];
  const float* Wlin  = (const float*)d_in[5];
  const float* blin  = (const float*)d_in[6];
  const float* Wself = (const float*)d_in[7];
  const float* bself = (const float*)d_in[8];
  const float* gam   = (const float*)d_in[9];
  const float* bet   = (const float*)d_in[10];
  const float* mean  = (const float*)d_in[11];
  const float* var   = (const float*)d_in[12];
  float* h = (float*)d_out;

  char* ws = (char*)d_ws;
  size_t off = 0;
  auto alloc = [&](size_t bytes) -> char* {
    char* p = ws + off;
    off = (off + bytes + 255) & ~(size_t)255;
    return p;
  };
  int* knn       = (int*)alloc((size_t)B_ * S_ * K_ * 4);
  int* counts    = (int*)alloc((size_t)B_ * S_ * 4);
  int* row_start = (int*)alloc((size_t)B_ * (S_ + 1) * 4);
  int* cursor    = (int*)alloc((size_t)B_ * S_ * 4);
  int* col       = (int*)alloc((size_t)B_ * S_ * K_ * 4);
  unsigned short* Wt  = (unsigned short*)alloc((size_t)L_ * H_ * KT_ * 2);
  float* scale   = (float*)alloc((size_t)L_ * H_ * 4);
  float* shift   = (float*)alloc((size_t)L_ * H_ * 4);
  unsigned short* hbA = (unsigned short*)alloc((size_t)B_ * S_ * H_ * 2);
  unsigned short* hbB = (unsigned short*)alloc((size_t)B_ * S_ * H_ * 2);
  unsigned short* hkn = (unsigned short*)alloc((size_t)B_ * S_ * H_ * 2);
  unsigned short* zbuf = (unsigned short*)alloc(4096 * 2);

  hipMemsetAsync(counts, 0, (size_t)B_ * S_ * 4, stream);
  hipMemsetAsync(zbuf, 0, 4096 * 2, stream);
  knn_kernel<<<dim3(S_ / 4, B_), 256, 0, stream>>>(ca, knn);
  count_kernel<<<dim3(B_ * S_ * K_ / 256), 256, 0, stream>>>(knn, counts);
  scan_kernel<<<dim3(B_), 256, 0, stream>>>(counts, row_start, cursor);
  fill_kernel<<<dim3(B_ * S_ * K_ / 256), 256, 0, stream>>>(knn, cursor, col);
  sort_kernel<<<dim3(B_ * S_ / 256), 256, 0, stream>>>(row_start, col);
  prepw_kernel<<<dim3((int)((size_t)L_ * H_ * KT_ / 8 / 256)), 256, 0, stream>>>(Wlin, Wself, Wt);
  prepa_kernel<<<dim3(L_ * H_ / 256), 256, 0, stream>>>(gam, bet, mean, var, blin, bself, scale, shift);
  inith_kernel<<<dim3(B_ * S_ * (H_ / 4) / 256), 256, 0, stream>>>(ca, Wp, bp, h, hbA);

  for (int l = 0; l < L_; l++){
    unsigned short* in  = (l & 1) ? hbB : hbA;
    unsigned short* out = (l & 1) ? hbA : hbB;
    hknn_kernel<<<dim3(S_, B_), 128, 0, stream>>>(in, row_start, col, hkn);
    gemmf_kernel<<<dim3((B_ * S_ / 64) * 4), 256, 0, stream>>>(
        in, hkn, Wt + (size_t)l * H_ * KT_, h, out,
        scale + l * H_, shift + l * H_, zbuf);
  }
}

// Round 7
// 579.534 us; speedup vs baseline: 1.1614x; 1.1614x over previous
//
#include <hip/hip_runtime.h>
#include <stdint.h>

#define B_ 8
#define S_ 2048
#define H_ 512
#define R_ 7
#define K_ 10
#define L_ 4
#define KT_ 4096  // fused K dim: 7 relation slices + self slice
#define RH_ 3584  // R*H

typedef __attribute__((ext_vector_type(8))) short bf16x8;
typedef __attribute__((ext_vector_type(4))) float f32x4;
typedef __attribute__((ext_vector_type(4))) unsigned short u16x4;
typedef unsigned long long u64;

__device__ __forceinline__ unsigned short f2bf(float f){
  unsigned int u = __float_as_uint(f);
  u = (u + 0x7fffu + ((u >> 16) & 1u)) >> 16;  // RNE
  return (unsigned short)u;
}

__device__ __forceinline__ float bf2f(unsigned short s){
  return __uint_as_float(((unsigned int)s) << 16);
}

__device__ __forceinline__ f32x4 bf4load(const unsigned short* p){
  u16x4 v = *(const u16x4*)p;
  f32x4 o;
#pragma unroll
  for (int e = 0; e < 4; e++) o[e] = bf2f(v[e]);
  return o;
}

__device__ __forceinline__ void gload16(const void* g, void* lds){
  __builtin_amdgcn_global_load_lds(
      (const __attribute__((address_space(1))) unsigned int*)g,
      (__attribute__((address_space(3))) unsigned int*)lds, 16, 0, 0);
}

// ---------------- KNN: per (b,i) find 10 nearest (excl self), exact f32 ops ---
__global__ __launch_bounds__(256) void knn_kernel(const float* __restrict__ pos,
                                                  int* __restrict__ knn){
  __shared__ float4 p4[S_];
  int b = blockIdx.y;
  const float* p = pos + (size_t)b * S_ * 3;
  for (int idx = threadIdx.x; idx < S_; idx += 256){
    float4 v; v.x = p[idx*3+0]; v.y = p[idx*3+1]; v.z = p[idx*3+2]; v.w = 0.f;
    p4[idx] = v;
  }
  __syncthreads();
  int w = threadIdx.x >> 6, l = threadIdx.x & 63;
  int i = blockIdx.x * 4 + w;
  float4 pi = p4[i];
  float xi = pi.x, yi = pi.y, zi = pi.z;
  u64 best[10];
#pragma unroll
  for (int q = 0; q < 10; q++) best[q] = ~0ull;
  for (int j = l; j < S_; j += 64){
    if (j == i) continue;
    float4 pj = p4[j];
    float dx = __fsub_rn(xi, pj.x);
    float dy = __fsub_rn(yi, pj.y);
    float dz = __fsub_rn(zi, pj.z);
    float d2 = __fadd_rn(__fadd_rn(__fmul_rn(dx,dx), __fmul_rn(dy,dy)), __fmul_rn(dz,dz));
    u64 key = ((u64)__float_as_uint(d2) << 32) | (unsigned)j;  // lex (d2, j)
    if (key < best[9]){
      best[9] = key;
#pragma unroll
      for (int q = 9; q > 0; --q){      // one bubble pass (rest sorted)
        u64 a = best[q-1], c = best[q];
        u64 lo = a < c ? a : c, hi = a < c ? c : a;
        best[q-1] = lo; best[q] = hi;
      }
    }
  }
  int* out = knn + ((size_t)b * S_ + i) * K_;
#pragma unroll
  for (int t = 0; t < 10; t++){
    u64 cand = best[0];
    u64 m = cand;
#pragma unroll
    for (int o = 32; o; o >>= 1){
      u64 other = __shfl_xor(m, o);
      if (other < m) m = other;
    }
    if (cand == m){
#pragma unroll
      for (int q = 0; q < 9; q++) best[q] = best[q+1];
      best[9] = ~0ull;
    }
    if (l == 0) out[t] = (int)(unsigned)(m & 0xffffffffu);
  }
}

// ---------------- CSR build (transpose KNN adjacency) -----------------------
__global__ void count_kernel(const int* __restrict__ knn, int* __restrict__ counts){
  int idx = blockIdx.x * 256 + threadIdx.x;     // B*S*K total
  int b = idx / (S_ * K_);
  int d = knn[idx];
  atomicAdd(&counts[b * S_ + d], 1);
}

__global__ __launch_bounds__(256) void scan_kernel(const int* __restrict__ counts,
                                                   int* __restrict__ row_start,
                                                   int* __restrict__ cursor){
  __shared__ int lds[256];
  int b = blockIdx.x, t = threadIdx.x;
  int base = b * S_;
  int v[8]; int s = 0;
#pragma unroll
  for (int e = 0; e < 8; e++){ v[e] = s; s += counts[base + t*8 + e]; }
  lds[t] = s;
  __syncthreads();
  int total = s;
  for (int o = 1; o < 256; o <<= 1){
    int add = 0;
    if (t >= o) add = lds[t - o];
    __syncthreads();
    lds[t] += add;
    __syncthreads();
  }
  int ex = lds[t] - total;
  int rb = b * (S_ + 1);
#pragma unroll
  for (int e = 0; e < 8; e++){
    int val = ex + v[e];
    row_start[rb + t*8 + e] = val;
    cursor[base + t*8 + e] = val;
  }
  if (t == 255) row_start[rb + S_] = lds[255];
}

__global__ void fill_kernel(const int* __restrict__ knn, int* __restrict__ cursor,
                            int* __restrict__ col){
  int idx = blockIdx.x * 256 + threadIdx.x;     // B*S*K
  int b = idx / (S_ * K_);
  int i = (idx / K_) % S_;
  int d = knn[idx];
  int p = atomicAdd(&cursor[b * S_ + d], 1);
  col[(size_t)b * S_ * K_ + p] = i;
}

__global__ void sort_kernel(const int* __restrict__ row_start, int* __restrict__ col){
  int idx = blockIdx.x * 256 + threadIdx.x;     // B*S
  int b = idx / S_, d = idx % S_;
  int rs = row_start[b*(S_+1)+d], re = row_start[b*(S_+1)+d+1];
  int* c = col + (size_t)b * S_ * K_;
  for (int a = rs + 1; a < re; ++a){
    int vv = c[a]; int q = a - 1;
    while (q >= rs && c[q] > vv){ c[q+1] = c[q]; --q; }
    c[q+1] = vv;
  }
}

// ---------------- weight prep: Wt[l][j=512][k=4096] = [Wlin[l][j] | Wself[l][j]]
__global__ void prepw_kernel(const float* __restrict__ Wlin, const float* __restrict__ Wself,
                             unsigned short* __restrict__ Wt){
  size_t e = ((size_t)blockIdx.x * 256 + threadIdx.x) * 8;   // L*512*4096 elements
  int k = (int)(e & 4095);
  int j = (int)((e >> 12) & 511);
  int l = (int)(e >> 21);
  const float* src = (k < RH_) ? Wlin + ((size_t)l * H_ + j) * RH_ + k
                               : Wself + ((size_t)l * H_ + j) * H_ + (k - RH_);
  union { unsigned short s[8]; uint4 u; } pk;
#pragma unroll
  for (int t = 0; t < 8; t++) pk.s[t] = f2bf(src[t]);
  *(uint4*)&Wt[e] = pk.u;
}

__global__ void prepa_kernel(const float* __restrict__ gam, const float* __restrict__ bet,
                             const float* __restrict__ mean, const float* __restrict__ var,
                             const float* __restrict__ blin, const float* __restrict__ bself,
                             float* __restrict__ scale, float* __restrict__ shift){
  int idx = blockIdx.x * 256 + threadIdx.x;     // L*H
  float sc = gam[idx] * rsqrtf(var[idx] + 1e-5f);
  scale[idx] = sc;
  shift[idx] = bet[idx] + (blin[idx] + bself[idx] - mean[idx]) * sc;
}

// ---------------- h0 = pos @ Wp.T + bp --------------------------------------
__global__ void inith_kernel(const float* __restrict__ pos, const float* __restrict__ Wp,
                             const float* __restrict__ bp, float* __restrict__ h,
                             unsigned short* __restrict__ hb){
  int idx = blockIdx.x * 256 + threadIdx.x;     // B*S*(H/4)
  int j = (idx & 127) * 4;
  int bs = idx >> 7;
  const float* p = pos + (size_t)bs * 3;
  float x = p[0], y = p[1], z = p[2];
  f32x4 o;
#pragma unroll
  for (int e = 0; e < 4; e++){
    const float* wr = Wp + (j + e) * 3;
    o[e] = x * wr[0] + y * wr[1] + z * wr[2] + bp[j + e];
  }
  *(f32x4*)&h[(size_t)bs * H_ + j] = o;
  unsigned int w0 = f2bf(o[0]) | ((unsigned)f2bf(o[1]) << 16);
  unsigned int w1 = f2bf(o[2]) | ((unsigned)f2bf(o[3]) << 16);
  uint2 u; u.x = w0; u.y = w1;
  *(uint2*)&hb[(size_t)bs * H_ + j] = u;
}

// ---------------- hknn[d] = sum_{i: d in knn(i)} hb[i]  (bf16 out) ----------
__global__ __launch_bounds__(128) void hknn_kernel(const unsigned short* __restrict__ hb,
                                                   const int* __restrict__ row_start,
                                                   const int* __restrict__ col,
                                                   unsigned short* __restrict__ hk){
  int bx = blockIdx.x;
  int d = (bx & 7) * 256 + (bx >> 3);     // XCD-contiguous d chunks
  int b = blockIdx.y;
  int j = threadIdx.x * 4;
  int rs = row_start[b * (S_ + 1) + d];
  int re = row_start[b * (S_ + 1) + d + 1];
  const int* cl = col + (size_t)b * S_ * K_;
  f32x4 acc = {0.f, 0.f, 0.f, 0.f};
  for (int e = rs; e < re; ++e){
    int i = cl[e];
    acc += bf4load(&hb[((size_t)b * S_ + i) * H_ + j]);
  }
  u16x4 v;
#pragma unroll
  for (int e = 0; e < 4; e++) v[e] = f2bf(acc[e]);
  *(u16x4*)&hk[((size_t)b * S_ + d) * H_ + j] = v;
}

// ---------------- fused GEMM: out = [shifted-h slices | hknn | h] @ Wt.T ----
// M=16384, N=512, K=4096. BM=128, BN=256, BK=64 -> grid 256 (1 block/CU).
// 8 waves (2M x 4N) of 64x64 (4x4 frags). 3-slot LDS ring (144 KB), prefetch
// depth 2 K-tiles, 2 phases/K-tile (m201-style): {8 ds_read | stage 3 gloads |
// barrier | lgkmcnt(0) | setprio | 16 MFMA | setprio | barrier}; one counted
// vmcnt(6) per K-tile. 8x16B chunk XOR swizzle (phys = logical ^ (row&7)) via
// pre-swizzled global source. Epilogue: BN affine + relu + residual.
__global__ __launch_bounds__(512) void gemmf_kernel(
    const unsigned short* __restrict__ hbin,
    const unsigned short* __restrict__ hkn,
    const unsigned short* __restrict__ Wt,     // [512][4096] this layer
    float* __restrict__ h,
    unsigned short* __restrict__ hbout,
    const float* __restrict__ scale,           // [512] this layer
    const float* __restrict__ shift,
    const unsigned short* __restrict__ zbuf){
  __shared__ unsigned short As[3][128 * 64];   // 48 KB
  __shared__ unsigned short Bs[3][256 * 64];   // 96 KB
  int tid = threadIdx.x;
  int wg = blockIdx.x;                 // 256 blocks
  int swz = (wg & 7) * 32 + (wg >> 3); // bijective XCD swizzle (256 % 8 == 0)
  int my = swz >> 1;                   // 128 M tiles
  int nx = swz & 1;                    // 2 N tiles (fastest -> same XCD shares A)
  int l = tid & 63, wid = tid >> 6;
  int wm = wid >> 2, wn = wid & 3;     // 2M x 4N waves of 64x64
  f32x4 acc[4][4] = {};

  // ---- staging coords: A 2 loads/thread, B 4 loads/thread per K-tile ----
  int arow = tid >> 3;                               // 0..63
  int lA8 = ((tid & 7) ^ (arow & 7)) << 3;           // logical chunk * 8 (elems)
  int gr0 = my * 128 + arow, gr1 = gr0 + 64;
  const unsigned short* Bp0 = Wt + (size_t)(nx * 256 +   0 + arow) * KT_ + lA8;
  const unsigned short* Bp1 = Wt + (size_t)(nx * 256 +  64 + arow) * KT_ + lA8;
  const unsigned short* Bp2 = Wt + (size_t)(nx * 256 + 128 + arow) * KT_ + lA8;
  const unsigned short* Bp3 = Wt + (size_t)(nx * 256 + 192 + arow) * KT_ + lA8;
  const unsigned short *sa0, *sa1;

#define SETSLC(rr) do {                                                       \
    int _r = (rr);                                                            \
    const unsigned short *_b0, *_b1;                                          \
    if (_r < 6){                                                              \
      int _sh = (_r < 3) ? (3 - _r) : (2 - _r);    /* src = d - off_r */      \
      int _s0 = gr0 + _sh, _s1 = gr1 + _sh;                                   \
      _b0 = (((unsigned)_s0 >> 11) == ((unsigned)gr0 >> 11)) ? hbin + (size_t)_s0 * H_ : zbuf; \
      _b1 = (((unsigned)_s1 >> 11) == ((unsigned)gr1 >> 11)) ? hbin + (size_t)_s1 * H_ : zbuf; \
    } else {                                                                  \
      const unsigned short* _bb = (_r == 6) ? hkn : hbin;                     \
      _b0 = _bb + (size_t)gr0 * H_; _b1 = _bb + (size_t)gr1 * H_;             \
    }                                                                         \
    sa0 = _b0 + lA8; sa1 = _b1 + lA8;                                         \
  } while (0)

  int dA0 = tid * 8, dA1 = (512 + tid) * 8;
  int dB0 = tid * 8, dB1 = (512 + tid) * 8, dB2 = (1024 + tid) * 8, dB3 = (1536 + tid) * 8;

  // ---- prologue: stage tiles 0 and 1 (both slice 0) ----
  SETSLC(0);
  gload16(sa0 +  0, &As[0][dA0]); gload16(sa1 +  0, &As[0][dA1]);
  gload16(Bp0 +  0, &Bs[0][dB0]); gload16(Bp1 +  0, &Bs[0][dB1]);
  gload16(Bp2 +  0, &Bs[0][dB2]); gload16(Bp3 +  0, &Bs[0][dB3]);
  gload16(sa0 + 64, &As[1][dA0]); gload16(sa1 + 64, &As[1][dA1]);
  gload16(Bp0 + 64, &Bs[1][dB0]); gload16(Bp1 + 64, &Bs[1][dB1]);
  gload16(Bp2 + 64, &Bs[1][dB2]); gload16(Bp3 + 64, &Bs[1][dB3]);
  asm volatile("s_waitcnt vmcnt(6)" ::: "memory");   // tile 0 landed
  __builtin_amdgcn_s_barrier();
  asm volatile("" ::: "memory");

  int kcr = l >> 4, lr = l & 15, lr7 = l & 7;
  int rA0 = wm * 64 + lr, rB0 = wn * 64 + lr;
  int s = 0;
#pragma unroll 1
  for (int t = 0; t < 64; ++t){
    int s2 = s + 2; if (s2 >= 3) s2 -= 3;
    int tt = t + 2;
    bool st = (t < 62);
    if (st) SETSLC(tt >> 3);
    int ko = (tt & 7) * 64;       // A offset within slice row
    int kb = tt * 64;             // B offset in fused k

    // ================= phase 0 (kk = 0) =================
    {
      int pc = (kcr ^ lr7) * 8;
      bf16x8 af[4], bf[4];
#pragma unroll
      for (int mi = 0; mi < 4; mi++)
        af[mi] = *(const bf16x8*)&As[s][(rA0 + mi * 16) * 64 + pc];
#pragma unroll
      for (int ni = 0; ni < 4; ni++)
        bf[ni] = *(const bf16x8*)&Bs[s][(rB0 + ni * 16) * 64 + pc];
      if (st){
        gload16(sa0 + ko, &As[s2][dA0]);
        gload16(sa1 + ko, &As[s2][dA1]);
        gload16(Bp0 + kb, &Bs[s2][dB0]);
      }
      __builtin_amdgcn_s_barrier();
      asm volatile("s_waitcnt lgkmcnt(0)" ::: "memory");
      __builtin_amdgcn_sched_barrier(0);
      __builtin_amdgcn_s_setprio(1);
#pragma unroll
      for (int mi = 0; mi < 4; mi++)
#pragma unroll
        for (int ni = 0; ni < 4; ni++)
          acc[mi][ni] = __builtin_amdgcn_mfma_f32_16x16x32_bf16(af[mi], bf[ni], acc[mi][ni], 0, 0, 0);
      __builtin_amdgcn_s_setprio(0);
      asm volatile("" ::: "memory");
      __builtin_amdgcn_s_barrier();
      asm volatile("" ::: "memory");
    }
    // ================= phase 1 (kk = 1) =================
    {
      int pc = ((4 + kcr) ^ lr7) * 8;
      bf16x8 af[4], bf[4];
#pragma unroll
      for (int mi = 0; mi < 4; mi++)
        af[mi] = *(const bf16x8*)&As[s][(rA0 + mi * 16) * 64 + pc];
#pragma unroll
      for (int ni = 0; ni < 4; ni++)
        bf[ni] = *(const bf16x8*)&Bs[s][(rB0 + ni * 16) * 64 + pc];
      if (st){
        gload16(Bp1 + kb, &Bs[s2][dB1]);
        gload16(Bp2 + kb, &Bs[s2][dB2]);
        gload16(Bp3 + kb, &Bs[s2][dB3]);
      }
      if (st)            asm volatile("s_waitcnt vmcnt(6)" ::: "memory");  // tile t+1 landed
      else if (t == 62)  asm volatile("s_waitcnt vmcnt(0)" ::: "memory");  // drain for last tile
      __builtin_amdgcn_s_barrier();
      asm volatile("s_waitcnt lgkmcnt(0)" ::: "memory");
      __builtin_amdgcn_sched_barrier(0);
      __builtin_amdgcn_s_setprio(1);
#pragma unroll
      for (int mi = 0; mi < 4; mi++)
#pragma unroll
        for (int ni = 0; ni < 4; ni++)
          acc[mi][ni] = __builtin_amdgcn_mfma_f32_16x16x32_bf16(af[mi], bf[ni], acc[mi][ni], 0, 0, 0);
      __builtin_amdgcn_s_setprio(0);
      asm volatile("" ::: "memory");
      __builtin_amdgcn_s_barrier();
      asm volatile("" ::: "memory");
    }
    ++s; if (s == 3) s = 0;
  }
#undef SETSLC

  // ---- epilogue: BN affine + relu + residual ----
  int r0 = (l >> 4) * 4, c0 = l & 15;
#pragma unroll
  for (int ni = 0; ni < 4; ni++){
    int gcol = nx * 256 + wn * 64 + ni * 16 + c0;
    float sc = scale[gcol], sf = shift[gcol];
#pragma unroll
    for (int mi = 0; mi < 4; mi++){
#pragma unroll
      for (int reg = 0; reg < 4; reg++){
        int grow = my * 128 + wm * 64 + mi * 16 + r0 + reg;
        size_t o = (size_t)grow * H_ + gcol;
        float val = fmaxf(acc[mi][ni][reg] * sc + sf, 0.f);
        float hv = h[o] + val;
        h[o] = hv;
        hbout[o] = f2bf(hv);
      }
    }
  }
}

extern "C" void kernel_launch(void* const* d_in, const int* in_sizes, int n_in,
                              void* d_out, int out_size, void* d_ws, size_t ws_size,
                              hipStream_t stream){
  const float* ca    = (const float*)d_in[1];
  const float* Wp    = (const float*)d_in[3];
  const float* bp    = (const float*)d_in[4];
  const float* Wlin  = (const float*)d_in[5];
  const float* blin  = (const float*)d_in[6];
  const float* Wself = (const float*)d_in[7];
  const float* bself = (const float*)d_in[8];
  const float* gam   = (const float*)d_in[9];
  const float* bet   = (const float*)d_in[10];
  const float* mean  = (const float*)d_in[11];
  const float* var   = (const float*)d_in[12];
  float* h = (float*)d_out;

  char* ws = (char*)d_ws;
  size_t off = 0;
  auto alloc = [&](size_t bytes) -> char* {
    char* p = ws + off;
    off = (off + bytes + 255) & ~(size_t)255;
    return p;
  };
  int* knn       = (int*)alloc((size_t)B_ * S_ * K_ * 4);
  int* counts    = (int*)alloc((size_t)B_ * S_ * 4);
  int* row_start = (int*)alloc((size_t)B_ * (S_ + 1) * 4);
  int* cursor    = (int*)alloc((size_t)B_ * S_ * 4);
  int* col       = (int*)alloc((size_t)B_ * S_ * K_ * 4);
  unsigned short* Wt  = (unsigned short*)alloc((size_t)L_ * H_ * KT_ * 2);
  float* scale   = (float*)alloc((size_t)L_ * H_ * 4);
  float* shift   = (float*)alloc((size_t)L_ * H_ * 4);
  unsigned short* hbA = (unsigned short*)alloc((size_t)B_ * S_ * H_ * 2);
  unsigned short* hbB = (unsigned short*)alloc((size_t)B_ * S_ * H_ * 2);
  unsigned short* hkn = (unsigned short*)alloc((size_t)B_ * S_ * H_ * 2);
  unsigned short* zbuf = (unsigned short*)alloc(4096 * 2);

  hipMemsetAsync(counts, 0, (size_t)B_ * S_ * 4, stream);
  hipMemsetAsync(zbuf, 0, 4096 * 2, stream);
  knn_kernel<<<dim3(S_ / 4, B_), 256, 0, stream>>>(ca, knn);
  count_kernel<<<dim3(B_ * S_ * K_ / 256), 256, 0, stream>>>(knn, counts);
  scan_kernel<<<dim3(B_), 256, 0, stream>>>(counts, row_start, cursor);
  fill_kernel<<<dim3(B_ * S_ * K_ / 256), 256, 0, stream>>>(knn, cursor, col);
  sort_kernel<<<dim3(B_ * S_ / 256), 256, 0, stream>>>(row_start, col);
  prepw_kernel<<<dim3((int)((size_t)L_ * H_ * KT_ / 8 / 256)), 256, 0, stream>>>(Wlin, Wself, Wt);
  prepa_kernel<<<dim3(L_ * H_ / 256), 256, 0, stream>>>(gam, bet, mean, var, blin, bself, scale, shift);
  inith_kernel<<<dim3(B_ * S_ * (H_ / 4) / 256), 256, 0, stream>>>(ca, Wp, bp, h, hbA);

  for (int l = 0; l < L_; l++){
    unsigned short* in  = (l & 1) ? hbB : hbA;
    unsigned short* out = (l & 1) ? hbA : hbB;
    hknn_kernel<<<dim3(S_, B_), 128, 0, stream>>>(in, row_start, col, hkn);
    gemmf_kernel<<<dim3(256), 512, 0, stream>>>(
        in, hkn, Wt + (size_t)l * H_ * KT_, h, out,
        scale + l * H_, shift + l * H_, zbuf);
  }
}

// Round 8
// 565.137 us; speedup vs baseline: 1.1910x; 1.0255x over previous
//
#include <hip/hip_runtime.h>
#include <stdint.h>

#define B_ 8
#define S_ 2048
#define H_ 512
#define R_ 7
#define K_ 10
#define L_ 4
#define KT_ 4096  // fused K dim: 7 relation slices + self slice
#define RH_ 3584  // R*H

typedef __attribute__((ext_vector_type(8))) short bf16x8;
typedef __attribute__((ext_vector_type(4))) float f32x4;
typedef __attribute__((ext_vector_type(4))) unsigned short u16x4;
typedef unsigned long long u64;

__device__ __forceinline__ unsigned short f2bf(float f){
  unsigned int u = __float_as_uint(f);
  u = (u + 0x7fffu + ((u >> 16) & 1u)) >> 16;  // RNE
  return (unsigned short)u;
}

__device__ __forceinline__ float bf2f(unsigned short s){
  return __uint_as_float(((unsigned int)s) << 16);
}

__device__ __forceinline__ f32x4 bf4load(const unsigned short* p){
  u16x4 v = *(const u16x4*)p;
  f32x4 o;
#pragma unroll
  for (int e = 0; e < 4; e++) o[e] = bf2f(v[e]);
  return o;
}

__device__ __forceinline__ void gload16(const void* g, void* lds){
  __builtin_amdgcn_global_load_lds(
      (const __attribute__((address_space(1))) unsigned int*)g,
      (__attribute__((address_space(3))) unsigned int*)lds, 16, 0, 0);
}

// ---------------- KNN: per (b,i) find 10 nearest (excl self), exact f32 ops ---
__global__ __launch_bounds__(256) void knn_kernel(const float* __restrict__ pos,
                                                  int* __restrict__ knn){
  __shared__ float4 p4[S_];
  int b = blockIdx.y;
  const float* p = pos + (size_t)b * S_ * 3;
  for (int idx = threadIdx.x; idx < S_; idx += 256){
    float4 v; v.x = p[idx*3+0]; v.y = p[idx*3+1]; v.z = p[idx*3+2]; v.w = 0.f;
    p4[idx] = v;
  }
  __syncthreads();
  int w = threadIdx.x >> 6, l = threadIdx.x & 63;
  int i = blockIdx.x * 4 + w;
  float4 pi = p4[i];
  float xi = pi.x, yi = pi.y, zi = pi.z;
  u64 best[10];
#pragma unroll
  for (int q = 0; q < 10; q++) best[q] = ~0ull;
  for (int j = l; j < S_; j += 64){
    if (j == i) continue;
    float4 pj = p4[j];
    float dx = __fsub_rn(xi, pj.x);
    float dy = __fsub_rn(yi, pj.y);
    float dz = __fsub_rn(zi, pj.z);
    float d2 = __fadd_rn(__fadd_rn(__fmul_rn(dx,dx), __fmul_rn(dy,dy)), __fmul_rn(dz,dz));
    u64 key = ((u64)__float_as_uint(d2) << 32) | (unsigned)j;  // lex (d2, j)
    if (key < best[9]){
      best[9] = key;
#pragma unroll
      for (int q = 9; q > 0; --q){      // one bubble pass (rest sorted)
        u64 a = best[q-1], c = best[q];
        u64 lo = a < c ? a : c, hi = a < c ? c : a;
        best[q-1] = lo; best[q] = hi;
      }
    }
  }
  int* out = knn + ((size_t)b * S_ + i) * K_;
#pragma unroll
  for (int t = 0; t < 10; t++){
    u64 cand = best[0];
    u64 m = cand;
#pragma unroll
    for (int o = 32; o; o >>= 1){
      u64 other = __shfl_xor(m, o);
      if (other < m) m = other;
    }
    if (cand == m){
#pragma unroll
      for (int q = 0; q < 9; q++) best[q] = best[q+1];
      best[9] = ~0ull;
    }
    if (l == 0) out[t] = (int)(unsigned)(m & 0xffffffffu);
  }
}

// ---------------- CSR build (transpose KNN adjacency) -----------------------
__global__ void count_kernel(const int* __restrict__ knn, int* __restrict__ counts){
  int idx = blockIdx.x * 256 + threadIdx.x;     // B*S*K total
  int b = idx / (S_ * K_);
  int d = knn[idx];
  atomicAdd(&counts[b * S_ + d], 1);
}

__global__ __launch_bounds__(256) void scan_kernel(const int* __restrict__ counts,
                                                   int* __restrict__ row_start,
                                                   int* __restrict__ cursor){
  __shared__ int lds[256];
  int b = blockIdx.x, t = threadIdx.x;
  int base = b * S_;
  int v[8]; int s = 0;
#pragma unroll
  for (int e = 0; e < 8; e++){ v[e] = s; s += counts[base + t*8 + e]; }
  lds[t] = s;
  __syncthreads();
  int total = s;
  for (int o = 1; o < 256; o <<= 1){
    int add = 0;
    if (t >= o) add = lds[t - o];
    __syncthreads();
    lds[t] += add;
    __syncthreads();
  }
  int ex = lds[t] - total;
  int rb = b * (S_ + 1);
#pragma unroll
  for (int e = 0; e < 8; e++){
    int val = ex + v[e];
    row_start[rb + t*8 + e] = val;
    cursor[base + t*8 + e] = val;
  }
  if (t == 255) row_start[rb + S_] = lds[255];
}

__global__ void fill_kernel(const int* __restrict__ knn, int* __restrict__ cursor,
                            int* __restrict__ col){
  int idx = blockIdx.x * 256 + threadIdx.x;     // B*S*K
  int b = idx / (S_ * K_);
  int i = (idx / K_) % S_;
  int d = knn[idx];
  int p = atomicAdd(&cursor[b * S_ + d], 1);
  col[(size_t)b * S_ * K_ + p] = i;
}

__global__ void sort_kernel(const int* __restrict__ row_start, int* __restrict__ col){
  int idx = blockIdx.x * 256 + threadIdx.x;     // B*S
  int b = idx / S_, d = idx % S_;
  int rs = row_start[b*(S_+1)+d], re = row_start[b*(S_+1)+d+1];
  int* c = col + (size_t)b * S_ * K_;
  for (int a = rs + 1; a < re; ++a){
    int vv = c[a]; int q = a - 1;
    while (q >= rs && c[q] > vv){ c[q+1] = c[q]; --q; }
    c[q+1] = vv;
  }
}

// ---------------- weight prep: Wt[l][j=512][k=4096] = [Wlin[l][j] | Wself[l][j]]
__global__ void prepw_kernel(const float* __restrict__ Wlin, const float* __restrict__ Wself,
                             unsigned short* __restrict__ Wt){
  size_t e = ((size_t)blockIdx.x * 256 + threadIdx.x) * 8;   // L*512*4096 elements
  int k = (int)(e & 4095);
  int j = (int)((e >> 12) & 511);
  int l = (int)(e >> 21);
  const float* src = (k < RH_) ? Wlin + ((size_t)l * H_ + j) * RH_ + k
                               : Wself + ((size_t)l * H_ + j) * H_ + (k - RH_);
  union { unsigned short s[8]; uint4 u; } pk;
#pragma unroll
  for (int t = 0; t < 8; t++) pk.s[t] = f2bf(src[t]);
  *(uint4*)&Wt[e] = pk.u;
}

__global__ void prepa_kernel(const float* __restrict__ gam, const float* __restrict__ bet,
                             const float* __restrict__ mean, const float* __restrict__ var,
                             const float* __restrict__ blin, const float* __restrict__ bself,
                             float* __restrict__ scale, float* __restrict__ shift){
  int idx = blockIdx.x * 256 + threadIdx.x;     // L*H
  float sc = gam[idx] * rsqrtf(var[idx] + 1e-5f);
  scale[idx] = sc;
  shift[idx] = bet[idx] + (blin[idx] + bself[idx] - mean[idx]) * sc;
}

// ---------------- h0 = pos @ Wp.T + bp --------------------------------------
__global__ void inith_kernel(const float* __restrict__ pos, const float* __restrict__ Wp,
                             const float* __restrict__ bp, float* __restrict__ h,
                             unsigned short* __restrict__ hb){
  int idx = blockIdx.x * 256 + threadIdx.x;     // B*S*(H/4)
  int j = (idx & 127) * 4;
  int bs = idx >> 7;
  const float* p = pos + (size_t)bs * 3;
  float x = p[0], y = p[1], z = p[2];
  f32x4 o;
#pragma unroll
  for (int e = 0; e < 4; e++){
    const float* wr = Wp + (j + e) * 3;
    o[e] = x * wr[0] + y * wr[1] + z * wr[2] + bp[j + e];
  }
  *(f32x4*)&h[(size_t)bs * H_ + j] = o;
  unsigned int w0 = f2bf(o[0]) | ((unsigned)f2bf(o[1]) << 16);
  unsigned int w1 = f2bf(o[2]) | ((unsigned)f2bf(o[3]) << 16);
  uint2 u; u.x = w0; u.y = w1;
  *(uint2*)&hb[(size_t)bs * H_ + j] = u;
}

// ---------------- hknn[d] = sum_{i: d in knn(i)} hb[i]  (bf16 out) ----------
__global__ __launch_bounds__(128) void hknn_kernel(const unsigned short* __restrict__ hb,
                                                   const int* __restrict__ row_start,
                                                   const int* __restrict__ col,
                                                   unsigned short* __restrict__ hk){
  int bx = blockIdx.x;
  int d = (bx & 7) * 256 + (bx >> 3);     // XCD-contiguous d chunks
  int b = blockIdx.y;
  int j = threadIdx.x * 4;
  int rs = row_start[b * (S_ + 1) + d];
  int re = row_start[b * (S_ + 1) + d + 1];
  const int* cl = col + (size_t)b * S_ * K_;
  f32x4 acc = {0.f, 0.f, 0.f, 0.f};
  for (int e = rs; e < re; ++e){
    int i = cl[e];
    acc += bf4load(&hb[((size_t)b * S_ + i) * H_ + j]);
  }
  u16x4 v;
#pragma unroll
  for (int e = 0; e < 4; e++) v[e] = f2bf(acc[e]);
  *(u16x4*)&hk[((size_t)b * S_ + d) * H_ + j] = v;
}

// ---------------- fused GEMM: out = [shifted-h slices | hknn | h] @ Wt.T ----
// M=16384, N=512, K=4096. BM=128, BN=256, BK=64 -> grid 256 (1 block/CU).
// 8 waves (2M x 4N) of 64x64 (4x4 frags). 3-slot LDS ring (144 KB), prefetch
// depth 2 K-tiles. ONE phase per K-tile (32 MFMA per barrier pair):
// {vmcnt(6) | barrier | 16 ds_read_b128 | stage 6 gloads (t+2) | lgkmcnt(0) |
//  sched_barrier | setprio | 32 MFMA | setprio | barrier}.
// 8x16B chunk XOR swizzle (phys = logical ^ (row&7)) via pre-swizzled source.
// Epilogue: BN affine + relu + residual.
__global__ __launch_bounds__(512) void gemmf_kernel(
    const unsigned short* __restrict__ hbin,
    const unsigned short* __restrict__ hkn,
    const unsigned short* __restrict__ Wt,     // [512][4096] this layer
    float* __restrict__ h,
    unsigned short* __restrict__ hbout,
    const float* __restrict__ scale,           // [512] this layer
    const float* __restrict__ shift,
    const unsigned short* __restrict__ zbuf){
  __shared__ unsigned short As[3][128 * 64];   // 48 KB
  __shared__ unsigned short Bs[3][256 * 64];   // 96 KB
  int tid = threadIdx.x;
  int wg = blockIdx.x;                 // 256 blocks
  int swz = (wg & 7) * 32 + (wg >> 3); // bijective XCD swizzle (256 % 8 == 0)
  int my = swz >> 1;                   // 128 M tiles
  int nx = swz & 1;                    // 2 N tiles (fastest -> same XCD shares A)
  int l = tid & 63, wid = tid >> 6;
  int wm = wid >> 2, wn = wid & 3;     // 2M x 4N waves of 64x64
  f32x4 acc[4][4] = {};

  // ---- staging coords: A 2 loads/thread, B 4 loads/thread per K-tile ----
  int arow = tid >> 3;                               // 0..63
  int lA8 = ((tid & 7) ^ (arow & 7)) << 3;           // logical chunk * 8 (elems)
  int gr0 = my * 128 + arow, gr1 = gr0 + 64;
  const unsigned short* Bp0 = Wt + (size_t)(nx * 256 +   0 + arow) * KT_ + lA8;
  const unsigned short* Bp1 = Wt + (size_t)(nx * 256 +  64 + arow) * KT_ + lA8;
  const unsigned short* Bp2 = Wt + (size_t)(nx * 256 + 128 + arow) * KT_ + lA8;
  const unsigned short* Bp3 = Wt + (size_t)(nx * 256 + 192 + arow) * KT_ + lA8;
  const unsigned short *sa0, *sa1;

#define SETSLC(rr) do {                                                       \
    int _r = (rr);                                                            \
    const unsigned short *_b0, *_b1;                                          \
    if (_r < 6){                                                              \
      int _sh = (_r < 3) ? (3 - _r) : (2 - _r);    /* src = d - off_r */      \
      int _s0 = gr0 + _sh, _s1 = gr1 + _sh;                                   \
      _b0 = (((unsigned)_s0 >> 11) == ((unsigned)gr0 >> 11)) ? hbin + (size_t)_s0 * H_ : zbuf; \
      _b1 = (((unsigned)_s1 >> 11) == ((unsigned)gr1 >> 11)) ? hbin + (size_t)_s1 * H_ : zbuf; \
    } else {                                                                  \
      const unsigned short* _bb = (_r == 6) ? hkn : hbin;                     \
      _b0 = _bb + (size_t)gr0 * H_; _b1 = _bb + (size_t)gr1 * H_;             \
    }                                                                         \
    sa0 = _b0 + lA8; sa1 = _b1 + lA8;                                         \
  } while (0)

  int dA0 = tid * 8, dA1 = (512 + tid) * 8;
  int dB0 = tid * 8, dB1 = (512 + tid) * 8, dB2 = (1024 + tid) * 8, dB3 = (1536 + tid) * 8;

#define STAGE(sl, ko, kb) do {                             \
    gload16(sa0 + (ko), &As[sl][dA0]);                     \
    gload16(sa1 + (ko), &As[sl][dA1]);                     \
    gload16(Bp0 + (kb), &Bs[sl][dB0]);                     \
    gload16(Bp1 + (kb), &Bs[sl][dB1]);                     \
    gload16(Bp2 + (kb), &Bs[sl][dB2]);                     \
    gload16(Bp3 + (kb), &Bs[sl][dB3]);                     \
  } while (0)

  // ---- prologue: stage tiles 0 and 1 (both slice 0) ----
  SETSLC(0);
  STAGE(0, 0, 0);
  STAGE(1, 64, 64);

  int kcr = l >> 4, lr = l & 15, lr7 = l & 7;
  int rA0 = wm * 64 + lr, rB0 = wn * 64 + lr;
  int pc0 = (kcr ^ lr7) * 8;
  int pc1 = ((4 + kcr) ^ lr7) * 8;
  int s = 0;
#pragma unroll 1
  for (int t = 0; t < 64; ++t){
    int s2 = s + 2; if (s2 >= 3) s2 -= 3;
    int tt = t + 2;
    bool st = (t < 62);
    if (st) SETSLC(tt >> 3);

    // tile t's 6 loads landed; up to 12 outstanding (t+1, t+2)
    if (t < 63) asm volatile("s_waitcnt vmcnt(6)" ::: "memory");
    else        asm volatile("s_waitcnt vmcnt(0)" ::: "memory");
    __builtin_amdgcn_s_barrier();
    asm volatile("" ::: "memory");

    // 16 ds_read_b128: both 32-wide k-chunks of A and B frags
    bf16x8 af0[4], af1[4], bf0[4], bf1[4];
#pragma unroll
    for (int mi = 0; mi < 4; mi++){
      af0[mi] = *(const bf16x8*)&As[s][(rA0 + mi * 16) * 64 + pc0];
      af1[mi] = *(const bf16x8*)&As[s][(rA0 + mi * 16) * 64 + pc1];
    }
#pragma unroll
    for (int ni = 0; ni < 4; ni++){
      bf0[ni] = *(const bf16x8*)&Bs[s][(rB0 + ni * 16) * 64 + pc0];
      bf1[ni] = *(const bf16x8*)&Bs[s][(rB0 + ni * 16) * 64 + pc1];
    }
    // stage tile t+2 into slot s2 (its slot was drained by t-1's end barrier)
    if (st) STAGE(s2, (tt & 7) * 64, tt * 64);

    asm volatile("s_waitcnt lgkmcnt(0)" ::: "memory");
    __builtin_amdgcn_sched_barrier(0);
    __builtin_amdgcn_s_setprio(1);
#pragma unroll
    for (int mi = 0; mi < 4; mi++)
#pragma unroll
      for (int ni = 0; ni < 4; ni++){
        acc[mi][ni] = __builtin_amdgcn_mfma_f32_16x16x32_bf16(af0[mi], bf0[ni], acc[mi][ni], 0, 0, 0);
        acc[mi][ni] = __builtin_amdgcn_mfma_f32_16x16x32_bf16(af1[mi], bf1[ni], acc[mi][ni], 0, 0, 0);
      }
    __builtin_amdgcn_s_setprio(0);
    asm volatile("" ::: "memory");
    __builtin_amdgcn_s_barrier();     // all waves done reading slot s
    asm volatile("" ::: "memory");
    ++s; if (s == 3) s = 0;
  }
#undef STAGE
#undef SETSLC

  // ---- epilogue: BN affine + relu + residual ----
  int r0 = (l >> 4) * 4, c0 = l & 15;
#pragma unroll
  for (int ni = 0; ni < 4; ni++){
    int gcol = nx * 256 + wn * 64 + ni * 16 + c0;
    float sc = scale[gcol], sf = shift[gcol];
#pragma unroll
    for (int mi = 0; mi < 4; mi++){
#pragma unroll
      for (int reg = 0; reg < 4; reg++){
        int grow = my * 128 + wm * 64 + mi * 16 + r0 + reg;
        size_t o = (size_t)grow * H_ + gcol;
        float val = fmaxf(acc[mi][ni][reg] * sc + sf, 0.f);
        float hv = h[o] + val;
        h[o] = hv;
        hbout[o] = f2bf(hv);
      }
    }
  }
}

extern "C" void kernel_launch(void* const* d_in, const int* in_sizes, int n_in,
                              void* d_out, int out_size, void* d_ws, size_t ws_size,
                              hipStream_t stream){
  const float* ca    = (const float*)d_in[1];
  const float* Wp    = (const float*)d_in[3];
  const float* bp    = (const float*)d_in[4];
  const float* Wlin  = (const float*)d_in[5];
  const float* blin  = (const float*)d_in[6];
  const float* Wself = (const float*)d_in[7];
  const float* bself = (const float*)d_in[8];
  const float* gam   = (const float*)d_in[9];
  const float* bet   = (const float*)d_in[10];
  const float* mean  = (const float*)d_in[11];
  const float* var   = (const float*)d_in[12];
  float* h = (float*)d_out;

  char* ws = (char*)d_ws;
  size_t off = 0;
  auto alloc = [&](size_t bytes) -> char* {
    char* p = ws + off;
    off = (off + bytes + 255) & ~(size_t)255;
    return p;
  };
  int* knn       = (int*)alloc((size_t)B_ * S_ * K_ * 4);
  int* counts    = (int*)alloc((size_t)B_ * S_ * 4);
  int* row_start = (int*)alloc((size_t)B_ * (S_ + 1) * 4);
  int* cursor    = (int*)alloc((size_t)B_ * S_ * 4);
  int* col       = (int*)alloc((size_t)B_ * S_ * K_ * 4);
  unsigned short* Wt  = (unsigned short*)alloc((size_t)L_ * H_ * KT_ * 2);
  float* scale   = (float*)alloc((size_t)L_ * H_ * 4);
  float* shift   = (float*)alloc((size_t)L_ * H_ * 4);
  unsigned short* hbA = (unsigned short*)alloc((size_t)B_ * S_ * H_ * 2);
  unsigned short* hbB = (unsigned short*)alloc((size_t)B_ * S_ * H_ * 2);
  unsigned short* hkn = (unsigned short*)alloc((size_t)B_ * S_ * H_ * 2);
  unsigned short* zbuf = (unsigned short*)alloc(4096 * 2);

  hipMemsetAsync(counts, 0, (size_t)B_ * S_ * 4, stream);
  hipMemsetAsync(zbuf, 0, 4096 * 2, stream);
  knn_kernel<<<dim3(S_ / 4, B_), 256, 0, stream>>>(ca, knn);
  count_kernel<<<dim3(B_ * S_ * K_ / 256), 256, 0, stream>>>(knn, counts);
  scan_kernel<<<dim3(B_), 256, 0, stream>>>(counts, row_start, cursor);
  fill_kernel<<<dim3(B_ * S_ * K_ / 256), 256, 0, stream>>>(knn, cursor, col);
  sort_kernel<<<dim3(B_ * S_ / 256), 256, 0, stream>>>(row_start, col);
  prepw_kernel<<<dim3((int)((size_t)L_ * H_ * KT_ / 8 / 256)), 256, 0, stream>>>(Wlin, Wself, Wt);
  prepa_kernel<<<dim3(L_ * H_ / 256), 256, 0, stream>>>(gam, bet, mean, var, blin, bself, scale, shift);
  inith_kernel<<<dim3(B_ * S_ * (H_ / 4) / 256), 256, 0, stream>>>(ca, Wp, bp, h, hbA);

  for (int l = 0; l < L_; l++){
    unsigned short* in  = (l & 1) ? hbB : hbA;
    unsigned short* out = (l & 1) ? hbA : hbB;
    hknn_kernel<<<dim3(S_, B_), 128, 0, stream>>>(in, row_start, col, hkn);
    gemmf_kernel<<<dim3(256), 512, 0, stream>>>(
        in, hkn, Wt + (size_t)l * H_ * KT_, h, out,
        scale + l * H_, shift + l * H_, zbuf);
  }
}